// Round 2
// baseline (1060.969 us; speedup 1.0000x reference)
//
#include <hip/hip_runtime.h>
#include <hip/hip_bf16.h>

// Scatter-sum: out[node] += H[edge] for each edge with X_node[edge] == node.
// H: [NUM_EDGES=2e6, D=32] f32, X_node: [2e6] int32, out: [100000, 32] f32.
//
// R2: one lane per (edge, 4-col group). float4 coalesced read of H,
// 4x fire-and-forget hardware atomics (unsafeAtomicAdd -> global_atomic_add_f32,
// no CAS loop, no return-value dependency).

__global__ void AggrSum_46299747451335_kernel(const float* __restrict__ H,
                                              const int* __restrict__ X_node,
                                              float* __restrict__ out,
                                              int num_edges) {
    long long t = (long long)blockIdx.x * blockDim.x + threadIdx.x;
    long long total = (long long)num_edges * 8;   // 8 lanes per edge (4 cols each)
    if (t >= total) return;
    int edge = (int)(t >> 3);
    int q    = (int)(t & 7);          // column group: cols 4q .. 4q+3

    int node = X_node[edge];          // 8 lanes broadcast-read the same word

    const float4* h4 = (const float4*)(H + (long long)edge * 32 + q * 4);
    float4 v = *h4;                   // 16 B coalesced per lane

    float* o = out + (long long)node * 32 + q * 4;
    unsafeAtomicAdd(o + 0, v.x);
    unsafeAtomicAdd(o + 1, v.y);
    unsafeAtomicAdd(o + 2, v.z);
    unsafeAtomicAdd(o + 3, v.w);
}

extern "C" void kernel_launch(void* const* d_in, const int* in_sizes, int n_in,
                              void* d_out, int out_size, void* d_ws, size_t ws_size,
                              hipStream_t stream) {
    const float* H      = (const float*)d_in[0];
    const int*   X_node = (const int*)d_in[1];
    float*       out    = (float*)d_out;

    const int num_edges = in_sizes[0] / 32;   // H is [num_edges, 32]

    // d_out is re-poisoned to 0xAA before every timed launch — zero it first.
    hipMemsetAsync(d_out, 0, (size_t)out_size * sizeof(float), stream);

    long long total_threads = (long long)num_edges * 8;
    int block = 256;
    long long grid = (total_threads + block - 1) / block;
    AggrSum_46299747451335_kernel<<<(dim3)(unsigned)grid, block, 0, stream>>>(
        H, X_node, out, num_edges);
}

// Round 3
// 457.915 us; speedup vs baseline: 2.3170x; 2.3170x over previous
//
#include <hip/hip_runtime.h>
#include <hip/hip_bf16.h>

// Scatter-sum: out[node] += H[edge] for each edge with X_node[edge] == node.
// H: [NUM_EDGES=2e6, D=32] f32, X_node: [2e6] int32, out: [100000, 32] f32.
//
// R3: back to R1's layout — one thread per (edge, col): each atomic
// instruction's 64 lanes cover 2 contiguous 128B out-rows (TCC line-mergeable).
// Only change vs R1: unsafeAtomicAdd -> single global_atomic_add_f32
// (no CAS loop / no return dependency). R2 taught us strided atomics
// quadruple WRITE_SIZE; do not break per-instruction contiguity.

__global__ void AggrSum_46299747451335_kernel(const float* __restrict__ H,
                                              const int* __restrict__ X_node,
                                              float* __restrict__ out,
                                              int num_edges) {
    long long t = (long long)blockIdx.x * blockDim.x + threadIdx.x;
    long long total = (long long)num_edges * 32;
    if (t >= total) return;
    int edge = (int)(t >> 5);
    int col  = (int)(t & 31);
    int node = X_node[edge];           // 32 lanes broadcast-read same word
    float v = H[t];                    // fully coalesced
    unsafeAtomicAdd(&out[(long long)node * 32 + col], v);
}

extern "C" void kernel_launch(void* const* d_in, const int* in_sizes, int n_in,
                              void* d_out, int out_size, void* d_ws, size_t ws_size,
                              hipStream_t stream) {
    const float* H      = (const float*)d_in[0];
    const int*   X_node = (const int*)d_in[1];
    float*       out    = (float*)d_out;

    const int num_edges = in_sizes[0] / 32;   // H is [num_edges, 32]

    // d_out is re-poisoned to 0xAA before every timed launch — zero it first.
    hipMemsetAsync(d_out, 0, (size_t)out_size * sizeof(float), stream);

    long long total_threads = (long long)num_edges * 32;
    int block = 256;
    long long grid = (total_threads + block - 1) / block;
    AggrSum_46299747451335_kernel<<<(dim3)(unsigned)grid, block, 0, stream>>>(
        H, X_node, out, num_edges);
}